// Round 3
// baseline (2793.741 us; speedup 1.0000x reference)
//
#include <hip/hip_runtime.h>
#include <math.h>

// ---------------------------------------------------------------------------
// UniPhyFluidScan. B=4 T=32 C=8 H=128 W=128, Wf=65. 128 conv imgs, 1024 spectra.
//
// FFTs: 2-stage Cooley-Tukey (N=128=16x8), per-image workgroup (512 thr),
// in-place LDS stages with register staging (reads -> bar -> writes -> bar).
// Row r2c/c2r passes use the pack trick: two real rows = one complex FFT.
// Convs: analytic gradient chain (4 direct 3x3/1x1-derived passes), chunked
// dynamically by ws_size.
//
// ws layout (floats): [ R = max(conv scratch, XFH=17,039,360) | A 532,480 |
//                       GKY 8320 | GKX 8320 | K2 8320 | S3 16 | NORMS 256 ]
// ---------------------------------------------------------------------------

#define CC 8

__device__ __forceinline__ float sig_(float x){ return 1.f/(1.f+expf(-x)); }
__device__ __forceinline__ float dsilu_(float x){ float s = sig_(x); return s*(1.f + x*(1.f-s)); }

__device__ __forceinline__ float2 cmul_(float2 a, float2 t){
  return make_float2(fmaf(a.x,t.x,-a.y*t.y), fmaf(a.x,t.y, a.y*t.x));
}
__device__ __forceinline__ float2 cfma_(float2 a, float2 t, float2 acc){
  acc.x = fmaf(a.x,t.x,fmaf(-a.y,t.y,acc.x));
  acc.y = fmaf(a.x,t.y,fmaf( a.y,t.x,acc.y));
  return acc;
}

// ---------------- setup ----------------------------------------------------
__global__ void k_setup_misc(const float* __restrict__ c3w,
                             float* __restrict__ s3, float* __restrict__ norms){
  int t = threadIdx.x;
  if (t < 16){
    float s = 0.f;
    for (int co=0; co<8; ++co) s += c3w[co*16 + t];
    s3[t] = s;
  }
  norms[t] = 0.f;
}

// one thread per (wf,k): tid = wf*128 + k
__global__ void k_setup_grid(const float* __restrict__ dt, const float* __restrict__ w1,
                             const float* __restrict__ b1, const float* __restrict__ w2,
                             const float* __restrict__ b2,
                             float* __restrict__ gky_a, float* __restrict__ gkx_a,
                             float* __restrict__ k2_a, float2* __restrict__ A){
  int tid = blockIdx.x*blockDim.x + threadIdx.x;
  if (tid >= 65*128) return;
  int wf = tid >> 7, k = tid & 127;
  float ky = (float)(k < 64 ? k : k-128) * (1.f/128.f);
  float kx = (float)wf * (1.f/128.f);
  gky_a[tid] = ky; gkx_a[tid] = kx;
  float k2 = ky*ky + kx*kx;
  k2_a[tid] = (tid==0) ? 1.f : k2;
  float kphys = sqrtf(ky*ky + kx*kx);
  float omega[CC];
  #pragma unroll
  for (int c=0;c<CC;++c) omega[c] = b2[c];
  for (int j=0;j<64;++j){
    float hp = ky*w1[j] + kx*w1[64+j] + b1[j];
    float hv = hp * sig_(hp);
    #pragma unroll
    for (int c=0;c<CC;++c) omega[c] = fmaf(hv, w2[j*CC + c], omega[c]);
  }
  #pragma unroll
  for (int c=0;c<CC;++c) omega[c] += kphys;
  for (int b=0;b<4;++b){
    float d = dt[b];
    #pragma unroll
    for (int c=0;c<CC;++c){
      float ph = omega[c]*d;
      float sn, cs; sincosf(ph, &sn, &cs);
      A[(b*8+c)*8320 + tid] = make_float2(cs, sn);
    }
  }
}

// ---------------- conv family ----------------------------------------------
// MODE 0: z1 = conv1(x)+b1
// MODE 1: gz2 = s3*silu'(conv2(silu(in))+b2)
// MODE 2: gz1 = convT2(in) * silu'(aux)
// MODE 3: XT  = aux + dt[(nbase+n)/32]*convT1(in)
template<int CIN, int COUT, int MODE>
__global__ __launch_bounds__(256) void k_conv(const float* __restrict__ in,
                                              const float* __restrict__ wsrc,
                                              const float* __restrict__ bias,
                                              const float* __restrict__ aux,
                                              const float* __restrict__ dtp,
                                              float* __restrict__ out,
                                              int nbase){
  __shared__ float s_in[CIN*18*34];
  __shared__ __align__(16) float s_w[CIN*9*COUT];
  int n = blockIdx.z;
  int ox0 = blockIdx.x*32, oy0 = blockIdx.y*16;
  int tx = threadIdx.x, ty = threadIdx.y;
  int tid = ty*16 + tx;

  for (int i=tid; i<CIN*9*COUT; i+=256){
    int co = i % COUT; int r = i / COUT;   // r = ci*9+k
    float wv;
    if constexpr (MODE <= 1){
      wv = wsrc[co*(CIN*9) + r];
    } else {
      int ci = r/9, k = r - ci*9, ky = k/3, kx = k - ky*3;
      wv = wsrc[(ci*COUT+co)*9 + (2-ky)*3 + (2-kx)];
    }
    s_w[i] = wv;
  }
  const float* ip = in + (size_t)n*CIN*16384;
  for (int i=tid; i<CIN*612; i+=256){
    int ci = i/612; int p = i - ci*612; int py = p/34, px = p - py*34;
    int gy = oy0 + py - 1, gx = ox0 + px - 1;
    float v = 0.f;
    if ((unsigned)gy < 128u && (unsigned)gx < 128u) v = ip[(ci*128+gy)*128+gx];
    if constexpr (MODE == 1) v = v * sig_(v);
    s_in[i] = v;
  }
  __syncthreads();

  float a0[COUT], a1[COUT];
  #pragma unroll
  for (int co=0; co<COUT; ++co){
    float b = 0.f;
    if constexpr (MODE <= 1) b = bias[co];
    a0[co] = b; a1[co] = b;
  }
  for (int ci=0; ci<CIN; ++ci){
    const float* si = s_in + ci*612;
    #pragma unroll
    for (int ky=0; ky<3; ++ky){
      #pragma unroll
      for (int kx=0; kx<3; ++kx){
        float v0 = si[(ty+ky)*34 + tx+kx];
        float v1 = si[(ty+ky)*34 + tx+16+kx];
        const float4* wp = (const float4*)(s_w + (ci*9 + ky*3+kx)*COUT);
        #pragma unroll
        for (int q=0; q<COUT/4; ++q){
          float4 wv = wp[q];
          a0[4*q+0] = fmaf(wv.x, v0, a0[4*q+0]); a1[4*q+0] = fmaf(wv.x, v1, a1[4*q+0]);
          a0[4*q+1] = fmaf(wv.y, v0, a0[4*q+1]); a1[4*q+1] = fmaf(wv.y, v1, a1[4*q+1]);
          a0[4*q+2] = fmaf(wv.z, v0, a0[4*q+2]); a1[4*q+2] = fmaf(wv.z, v1, a1[4*q+2]);
          a0[4*q+3] = fmaf(wv.w, v0, a0[4*q+3]); a1[4*q+3] = fmaf(wv.w, v1, a1[4*q+3]);
        }
      }
    }
  }
  int oy = oy0+ty;
  float dtv = 0.f;
  if constexpr (MODE == 3) dtv = dtp[(nbase + n) >> 5];
  #pragma unroll
  for (int co=0; co<COUT; ++co){
    int i0 = ((n*COUT+co)*128+oy)*128 + ox0 + tx;
    int i1 = i0 + 16;
    if constexpr (MODE == 0){
      out[i0] = a0[co]; out[i1] = a1[co];
    } else if constexpr (MODE == 1){
      out[i0] = aux[co]*dsilu_(a0[co]);
      out[i1] = aux[co]*dsilu_(a1[co]);
    } else if constexpr (MODE == 2){
      out[i0] = a0[co]*dsilu_(aux[i0]);
      out[i1] = a1[co]*dsilu_(aux[i1]);
    } else {
      out[i0] = fmaf(dtv, a0[co], aux[i0]);
      out[i1] = fmaf(dtv, a1[co], aux[i1]);
    }
  }
}

// ---------------- forward rfft2, CT 16x8, pack trick ------------------------
// out layout: Xf[img][wf*128 + k], total scale 1/128 (ortho) with pack 0.5
// folded in -> 1/256 at final stage.
__global__ __launch_bounds__(512) void k_fft_fwd(const float* __restrict__ xt,
                                                 float2* __restrict__ X){
  __shared__ float2 s_buf[8320];
  __shared__ float2 s_tw[128];
  __shared__ float2 s_t16[16];
  __shared__ float2 s_t8[8];
  int img = blockIdx.x, tid = threadIdx.x;
  if (tid < 128){ float sn,cs; sincosf((float)tid*0.04908738521234052f,&sn,&cs); s_tw[tid]=make_float2(cs,-sn); }
  if (tid < 16) { float sn,cs; sincosf((float)tid*0.39269908169872414f,&sn,&cs); s_t16[tid]=make_float2(cs,-sn); }
  if (tid < 8)  { float sn,cs; sincosf((float)tid*0.7853981633974483f ,&sn,&cs); s_t8[tid]=make_float2(cs,-sn); }
  const float* xp = xt + (size_t)img*16384;
  // pack rows: s_buf[hp*128+w] = x[2hp][w] + i x[2hp+1][w]
  #pragma unroll
  for (int it=0; it<16; ++it){
    int j = it*512+tid; int hp=j>>7, w=j&127;
    s_buf[j] = make_float2(xp[hp*256 + w], xp[hp*256 + 128 + w]);
  }
  __syncthreads();
  float2 rg[17];
  // row stage 1: u[hp][n2*16+k1] = (sum_n1 z[8n1+n2] W16^{n1k1}) W128^{n2k1}
  #pragma unroll
  for (int it=0; it<16; ++it){
    int i = it*512+tid; int hp=i>>7, j=i&127, n2=j>>4, k1=j&15;
    float2 acc = make_float2(0.f,0.f);
    const float2* row = s_buf + hp*128 + n2;
    #pragma unroll
    for (int n1=0;n1<16;++n1) acc = cfma_(row[8*n1], s_t16[(n1*k1)&15], acc);
    rg[it] = cmul_(acc, s_tw[(n2*k1)&127]);
  }
  __syncthreads();
  #pragma unroll
  for (int it=0; it<16; ++it) s_buf[it*512+tid] = rg[it];
  __syncthreads();
  // row stage 2: Z[hp][k1+16k2] = sum_n2 u[n2*16+k1] W8^{n2k2}
  #pragma unroll
  for (int it=0; it<16; ++it){
    int i = it*512+tid; int hp=i>>7, k=i&127, k1=k&15, k2=k>>4;
    float2 acc = make_float2(0.f,0.f);
    const float2* u = s_buf + hp*128 + k1;
    #pragma unroll
    for (int n2=0;n2<8;++n2) acc = cfma_(u[16*n2], s_t8[(n2*k2)&7], acc);
    rg[it] = acc;
  }
  __syncthreads();
  #pragma unroll
  for (int it=0; it<16; ++it) s_buf[it*512+tid] = rg[it];
  __syncthreads();
  // col stage 1 with on-the-fly unpack (0.5 factor deferred):
  // y[h][wf]: h=8n1+n2, even: Z1+conj(Z2); odd: (Z1-conj(Z2))/i  (Z2 at 128-wf)
  #pragma unroll
  for (int it=0; it<17; ++it){
    int i = it*512+tid;
    if (i < 8320){
      int wf=i>>7, j=i&127, n2=j>>4, k1=j&15;
      int j2 = (128-wf)&127;
      int par = n2&1;
      float2 acc = make_float2(0.f,0.f);
      #pragma unroll
      for (int n1=0;n1<16;++n1){
        int hp = 4*n1 + (n2>>1);
        float2 Z1 = s_buf[hp*128+wf];
        float2 Z2 = s_buf[hp*128+j2];
        float yr = par ? (Z1.y+Z2.y) : (Z1.x+Z2.x);
        float yi = par ? (Z2.x-Z1.x) : (Z1.y-Z2.y);
        acc = cfma_(make_float2(yr,yi), s_t16[(n1*k1)&15], acc);
      }
      rg[it] = cmul_(acc, s_tw[(n2*k1)&127]);
    }
  }
  __syncthreads();
  #pragma unroll
  for (int it=0; it<17; ++it){ int i=it*512+tid; if(i<8320) s_buf[i]=rg[it]; }
  __syncthreads();
  // col stage 2 + scaled store
  float2* Xp = X + (size_t)img*8320;
  #pragma unroll
  for (int it=0; it<17; ++it){
    int i = it*512+tid;
    if (i < 8320){
      int wf=i>>7, k=i&127, k1=k&15, k2=k>>4;
      float2 acc = make_float2(0.f,0.f);
      const float2* u = s_buf + wf*128 + k1;
      #pragma unroll
      for (int n2=0;n2<8;++n2) acc = cfma_(u[16*n2], s_t8[(n2*k2)&7], acc);
      Xp[i] = make_float2(acc.x*(1.f/256.f), acc.y*(1.f/256.f));
    }
  }
}

// ---------------- fused projection+scan+projection+norms (in place) ---------
__global__ __launch_bounds__(256) void k_scan_fused(float2* __restrict__ X,
                                                    const float2* __restrict__ A2,
                                                    const float* __restrict__ gky,
                                                    const float* __restrict__ gkx,
                                                    const float* __restrict__ k2,
                                                    float* __restrict__ norms){
  int tid = blockIdx.x*256 + threadIdx.x;
  int cls = tid / 33280;
  int j   = tid - cls*33280;
  int b   = j / 8320;
  int r   = j - b*8320;           // wf*128 + k
  int lane0 = ((threadIdx.x & 63) == 0);

  if (cls == 0){
    float kyv = gky[r], kxv = gkx[r], ik2 = 1.f/k2[r];
    float2 a0 = A2[(b*8+0)*8320 + r];
    float2 a1 = A2[(b*8+1)*8320 + r];
    float h0r=0.f,h0i=0.f,h1r=0.f,h1i=0.f;
    for (int t=0; t<32; ++t){
      int base = ((b*32+t)*8)*8320 + r;
      float2 u = X[base];
      float2 v = X[base + 8320];
      float dr = (kyv*u.x + kxv*v.x)*ik2;
      float di = (kyv*u.y + kxv*v.y)*ik2;
      float uxr = u.x - kyv*dr, uxi = u.y - kyv*di;
      float vxr = v.x - kxv*dr, vxi = v.y - kxv*di;
      float ni = uxr*uxr + uxi*uxi + vxr*vxr + vxi*vxi;
      float n0r = a0.x*h0r - a0.y*h0i + uxr;
      float n0i = a0.x*h0i + a0.y*h0r + uxi;
      float n1r = a1.x*h1r - a1.y*h1i + vxr;
      float n1i = a1.x*h1i + a1.y*h1r + vxi;
      h0r=n0r; h0i=n0i; h1r=n1r; h1i=n1i;
      float er = (kyv*h0r + kxv*h1r)*ik2;
      float ei = (kyv*h0i + kxv*h1i)*ik2;
      float p0r = h0r - kyv*er, p0i = h0i - kyv*ei;
      float p1r = h1r - kxv*er, p1i = h1i - kxv*ei;
      float no = p0r*p0r + p0i*p0i + p1r*p1r + p1i*p1i;
      X[base]        = make_float2(p0r, p0i);
      X[base + 8320] = make_float2(p1r, p1i);
      #pragma unroll
      for (int off=32; off; off>>=1){ ni += __shfl_down(ni, off); no += __shfl_down(no, off); }
      if (lane0){ atomicAdd(&norms[(b*32+t)*2], ni); atomicAdd(&norms[(b*32+t)*2+1], no); }
    }
  } else {
    int c = cls + 1;
    float2 a = A2[(b*8+c)*8320 + r];
    float hr=0.f, hi=0.f;
    for (int t=0; t<32; ++t){
      int base = ((b*32+t)*8 + c)*8320 + r;
      float2 x = X[base];
      float ni = x.x*x.x + x.y*x.y;
      float nr = a.x*hr - a.y*hi + x.x;
      float nn = a.x*hi + a.y*hr + x.y;
      hr=nr; hi=nn;
      float no = hr*hr + hi*hi;
      X[base] = make_float2(hr, hi);
      #pragma unroll
      for (int off=32; off; off>>=1){ ni += __shfl_down(ni, off); no += __shfl_down(no, off); }
      if (lane0){ atomicAdd(&norms[(b*32+t)*2], ni); atomicAdd(&norms[(b*32+t)*2+1], no); }
    }
  }
}

// ---------------- inverse irfft2, CT 16x8, pack trick -----------------------
__global__ __launch_bounds__(512) void k_fft_inv(const float2* __restrict__ X,
                                                 const float* __restrict__ norms,
                                                 float* __restrict__ out){
  __shared__ float2 s_buf[8320];
  __shared__ float2 s_tw[128];
  __shared__ float2 s_t16[16];
  __shared__ float2 s_t8[8];
  int img = blockIdx.x, tid = threadIdx.x;
  if (tid < 128){ float sn,cs; sincosf((float)tid*0.04908738521234052f,&sn,&cs); s_tw[tid]=make_float2(cs,sn); }
  if (tid < 16) { float sn,cs; sincosf((float)tid*0.39269908169872414f,&sn,&cs); s_t16[tid]=make_float2(cs,sn); }
  if (tid < 8)  { float sn,cs; sincosf((float)tid*0.7853981633974483f ,&sn,&cs); s_t8[tid]=make_float2(cs,sn); }
  const float2* Xp = X + (size_t)img*8320;
  #pragma unroll
  for (int it=0; it<17; ++it){ int i=it*512+tid; if(i<8320) s_buf[i]=Xp[i]; }
  int bt = img >> 3;
  float scale = sqrtf(norms[bt*2]) / (sqrtf(norms[bt*2+1]) + 1e-6f) * (1.f/128.f);
  __syncthreads();
  float2 rg[17];
  // inv col stage 1 (input index k=8n1+n2)
  #pragma unroll
  for (int it=0; it<17; ++it){
    int i = it*512+tid;
    if (i < 8320){
      int wf=i>>7, j=i&127, n2=j>>4, k1=j&15;
      float2 acc = make_float2(0.f,0.f);
      const float2* row = s_buf + wf*128 + n2;
      #pragma unroll
      for (int n1=0;n1<16;++n1) acc = cfma_(row[8*n1], s_t16[(n1*k1)&15], acc);
      rg[it] = cmul_(acc, s_tw[(n2*k1)&127]);
    }
  }
  __syncthreads();
  #pragma unroll
  for (int it=0; it<17; ++it){ int i=it*512+tid; if(i<8320) s_buf[i]=rg[it]; }
  __syncthreads();
  // inv col stage 2 -> y[h][wf] (scaled), stored transposed at [h*65+wf]
  #pragma unroll
  for (int it=0; it<17; ++it){
    int i = it*512+tid;
    if (i < 8320){
      int wf=i>>7, h=i&127, k1=h&15, k2=h>>4;
      float2 acc = make_float2(0.f,0.f);
      const float2* u = s_buf + wf*128 + k1;
      #pragma unroll
      for (int n2=0;n2<8;++n2) acc = cfma_(u[16*n2], s_t8[(n2*k2)&7], acc);
      rg[it] = make_float2(acc.x*scale, acc.y*scale);
    }
  }
  __syncthreads();
  #pragma unroll
  for (int it=0; it<17; ++it){
    int i=it*512+tid;
    if (i<8320){ int wf=i>>7, h=i&127; s_buf[h*65+wf] = rg[it]; }
  }
  __syncthreads();
  // inv row stage 1 with on-the-fly Hermitian pack:
  // Z[wf'] = A+iB (wf'<=64, Im dropped at 0/64), conj(A)+i conj(B) (wf'>64)
  #pragma unroll
  for (int it=0; it<16; ++it){
    int i = it*512+tid; int hp=i>>7, j=i&127, n2=j>>4, k1=j&15;
    float2 acc = make_float2(0.f,0.f);
    #pragma unroll
    for (int n1=0;n1<16;++n1){
      int wfp = 8*n1 + n2;
      int neg = wfp > 64;
      int jj = neg ? 128-wfp : wfp;
      float2 Av = s_buf[(hp*2)*65 + jj];
      float2 Bv = s_buf[(hp*2+1)*65 + jj];
      if (jj == 0 || jj == 64){ Av.y = 0.f; Bv.y = 0.f; }
      float zr = neg ? (Av.x + Bv.y) : (Av.x - Bv.y);
      float zi = neg ? (Bv.x - Av.y) : (Av.y + Bv.x);
      acc = cfma_(make_float2(zr,zi), s_t16[(n1*k1)&15], acc);
    }
    rg[it] = cmul_(acc, s_tw[(n2*k1)&127]);
  }
  __syncthreads();
  #pragma unroll
  for (int it=0; it<16; ++it) s_buf[it*512+tid] = rg[it];
  __syncthreads();
  // inv row stage 2 -> z[w] = x[2hp][w] + i x[2hp+1][w], store to global
  float* op = out + (size_t)img*16384;
  #pragma unroll
  for (int it=0; it<16; ++it){
    int i = it*512+tid; int hp=i>>7, w=i&127, k1=w&15, k2=w>>4;
    float2 acc = make_float2(0.f,0.f);
    const float2* u = s_buf + hp*128 + k1;
    #pragma unroll
    for (int n2=0;n2<8;++n2) acc = cfma_(u[16*n2], s_t8[(n2*k2)&7], acc);
    op[hp*256 + w]       = acc.x;
    op[hp*256 + 128 + w] = acc.y;
  }
}

// ---------------------------------------------------------------------------
extern "C" void kernel_launch(void* const* d_in, const int* in_sizes, int n_in,
                              void* d_out, int out_size, void* d_ws, size_t ws_size,
                              hipStream_t stream) {
  const float* x_seq = (const float*)d_in[0];
  const float* dt    = (const float*)d_in[1];
  const float* pw1   = (const float*)d_in[2];
  const float* pb1   = (const float*)d_in[3];
  const float* pw2   = (const float*)d_in[4];
  const float* pb2   = (const float*)d_in[5];
  const float* c1w   = (const float*)d_in[6];
  const float* c1b   = (const float*)d_in[7];
  const float* c2w   = (const float*)d_in[8];
  const float* c2b   = (const float*)d_in[9];
  const float* c3w   = (const float*)d_in[10];
  float* out = (float*)d_out;
  float* ws  = (float*)d_ws;

  const size_t XFH_F  = 17039360;                 // 65*128*1024 float2 in floats
  const size_t TAIL_F = 532480 + 3*8320 + 16 + 256;
  size_t avail_f = ws_size / 4;

  int chunk = 16;
  for (int c = 128; c >= 16; c >>= 1){
    size_t scratch = (size_t)3*c*262144;
    size_t R = scratch > XFH_F ? scratch : XFH_F;
    if (R + TAIL_F <= avail_f){ chunk = c; break; }
  }
  size_t Rsz = (size_t)3*chunk*262144; if (Rsz < XFH_F) Rsz = XFH_F;

  float*  Aa   = ws + Rsz;
  float*  GKY  = Aa + 532480;
  float*  GKX  = GKY + 8320;
  float*  K2   = GKX + 8320;
  float*  S3   = K2  + 8320;
  float*  NORMS= S3  + 16;

  float2* XFH = (float2*)ws;
  float2* A2  = (float2*)Aa;

  float* CZ1  = ws;
  float* CGZ2 = ws + (size_t)chunk*262144;
  float* CGZ1 = ws + (size_t)2*chunk*262144;

  k_setup_misc<<<1, 256, 0, stream>>>(c3w, S3, NORMS);
  k_setup_grid<<<33, 256, 0, stream>>>(dt, pw1, pb1, pw2, pb2, GKY, GKX, K2, A2);

  dim3 cb(16,16), cg(4,8,chunk);
  for (int n0 = 0; n0 < 128; n0 += chunk){
    const float* xin = x_seq + (size_t)n0*8*16384;
    float*       xtp = out   + (size_t)n0*8*16384;   // XT staged in d_out
    k_conv<8,16,0><<<cg, cb, 0, stream>>>(xin, c1w, c1b, nullptr, nullptr, CZ1, n0);
    k_conv<16,16,1><<<cg, cb, 0, stream>>>(CZ1, c2w, c2b, S3, nullptr, CGZ2, n0);
    k_conv<16,16,2><<<cg, cb, 0, stream>>>(CGZ2, c2w, nullptr, CZ1, nullptr, CGZ1, n0);
    k_conv<16,8,3><<<cg, cb, 0, stream>>>(CGZ1, c1w, nullptr, xin, dt, xtp, n0);
  }

  k_fft_fwd<<<1024, 512, 0, stream>>>(out, XFH);
  k_scan_fused<<<910, 256, 0, stream>>>(XFH, A2, GKY, GKX, K2, NORMS);
  k_fft_inv<<<1024, 512, 0, stream>>>(XFH, NORMS, out);
}

// Round 4
// 1717.216 us; speedup vs baseline: 1.6269x; 1.6269x over previous
//
#include <hip/hip_runtime.h>
#include <math.h>

// ---------------------------------------------------------------------------
// UniPhyFluidScan. B=4 T=32 C=8 H=128 W=128, Wf=65. 128 conv imgs, 1024 spectra.
//
// FFTs: 2-stage Cooley-Tukey (N=128=16x8), per-image workgroup (1024 thr),
// ping-pong LDS buffers (no register staging across barriers -> no scratch
// spills; round-3 lesson: rg[17] arrays spilled 1.7GB/launch).
// Row r2c/c2r passes use the pack trick: two real rows = one complex FFT.
// Convs: analytic gradient chain (4 direct 3x3 passes), chunked by ws_size.
//
// ws layout (floats): [ R = max(conv scratch, XFH=17,039,360) | A 532,480 |
//                       GKY 8320 | GKX 8320 | K2 8320 | S3 16 | NORMS 256 ]
// ---------------------------------------------------------------------------

#define CC 8

__device__ __forceinline__ float sig_(float x){ return 1.f/(1.f+expf(-x)); }
__device__ __forceinline__ float dsilu_(float x){ float s = sig_(x); return s*(1.f + x*(1.f-s)); }

__device__ __forceinline__ float2 cmul_(float2 a, float2 t){
  return make_float2(fmaf(a.x,t.x,-a.y*t.y), fmaf(a.x,t.y, a.y*t.x));
}
__device__ __forceinline__ float2 cfma_(float2 a, float2 t, float2 acc){
  acc.x = fmaf(a.x,t.x,fmaf(-a.y,t.y,acc.x));
  acc.y = fmaf(a.x,t.y,fmaf( a.y,t.x,acc.y));
  return acc;
}

// ---------------- setup ----------------------------------------------------
__global__ void k_setup_misc(const float* __restrict__ c3w,
                             float* __restrict__ s3, float* __restrict__ norms){
  int t = threadIdx.x;
  if (t < 16){
    float s = 0.f;
    for (int co=0; co<8; ++co) s += c3w[co*16 + t];
    s3[t] = s;
  }
  norms[t] = 0.f;
}

// one thread per (wf,k): tid = wf*128 + k
__global__ void k_setup_grid(const float* __restrict__ dt, const float* __restrict__ w1,
                             const float* __restrict__ b1, const float* __restrict__ w2,
                             const float* __restrict__ b2,
                             float* __restrict__ gky_a, float* __restrict__ gkx_a,
                             float* __restrict__ k2_a, float2* __restrict__ A){
  int tid = blockIdx.x*blockDim.x + threadIdx.x;
  if (tid >= 65*128) return;
  int wf = tid >> 7, k = tid & 127;
  float ky = (float)(k < 64 ? k : k-128) * (1.f/128.f);
  float kx = (float)wf * (1.f/128.f);
  gky_a[tid] = ky; gkx_a[tid] = kx;
  float k2 = ky*ky + kx*kx;
  k2_a[tid] = (tid==0) ? 1.f : k2;
  float kphys = sqrtf(ky*ky + kx*kx);
  float omega[CC];
  #pragma unroll
  for (int c=0;c<CC;++c) omega[c] = b2[c];
  for (int j=0;j<64;++j){
    float hp = ky*w1[j] + kx*w1[64+j] + b1[j];
    float hv = hp * sig_(hp);
    #pragma unroll
    for (int c=0;c<CC;++c) omega[c] = fmaf(hv, w2[j*CC + c], omega[c]);
  }
  #pragma unroll
  for (int c=0;c<CC;++c) omega[c] += kphys;
  for (int b=0;b<4;++b){
    float d = dt[b];
    #pragma unroll
    for (int c=0;c<CC;++c){
      float ph = omega[c]*d;
      float sn, cs; sincosf(ph, &sn, &cs);
      A[(b*8+c)*8320 + tid] = make_float2(cs, sn);
    }
  }
}

// ---------------- conv family ----------------------------------------------
// MODE 0: z1 = conv1(x)+b1
// MODE 1: gz2 = s3*silu'(conv2(silu(in))+b2)
// MODE 2: gz1 = convT2(in) * silu'(aux)
// MODE 3: XT  = aux + dt[(nbase+n)/32]*convT1(in)
template<int CIN, int COUT, int MODE>
__global__ __launch_bounds__(256) void k_conv(const float* __restrict__ in,
                                              const float* __restrict__ wsrc,
                                              const float* __restrict__ bias,
                                              const float* __restrict__ aux,
                                              const float* __restrict__ dtp,
                                              float* __restrict__ out,
                                              int nbase){
  __shared__ float s_in[CIN*18*34];
  __shared__ __align__(16) float s_w[CIN*9*COUT];
  int n = blockIdx.z;
  int ox0 = blockIdx.x*32, oy0 = blockIdx.y*16;
  int tx = threadIdx.x, ty = threadIdx.y;
  int tid = ty*16 + tx;

  for (int i=tid; i<CIN*9*COUT; i+=256){
    int co = i % COUT; int r = i / COUT;   // r = ci*9+k
    float wv;
    if constexpr (MODE <= 1){
      wv = wsrc[co*(CIN*9) + r];
    } else {
      int ci = r/9, k = r - ci*9, ky = k/3, kx = k - ky*3;
      wv = wsrc[(ci*COUT+co)*9 + (2-ky)*3 + (2-kx)];
    }
    s_w[i] = wv;
  }
  const float* ip = in + (size_t)n*CIN*16384;
  for (int i=tid; i<CIN*612; i+=256){
    int ci = i/612; int p = i - ci*612; int py = p/34, px = p - py*34;
    int gy = oy0 + py - 1, gx = ox0 + px - 1;
    float v = 0.f;
    if ((unsigned)gy < 128u && (unsigned)gx < 128u) v = ip[(ci*128+gy)*128+gx];
    if constexpr (MODE == 1) v = v * sig_(v);
    s_in[i] = v;
  }
  __syncthreads();

  float a0[COUT], a1[COUT];
  #pragma unroll
  for (int co=0; co<COUT; ++co){
    float b = 0.f;
    if constexpr (MODE <= 1) b = bias[co];
    a0[co] = b; a1[co] = b;
  }
  for (int ci=0; ci<CIN; ++ci){
    const float* si = s_in + ci*612;
    #pragma unroll
    for (int ky=0; ky<3; ++ky){
      #pragma unroll
      for (int kx=0; kx<3; ++kx){
        float v0 = si[(ty+ky)*34 + tx+kx];
        float v1 = si[(ty+ky)*34 + tx+16+kx];
        const float4* wp = (const float4*)(s_w + (ci*9 + ky*3+kx)*COUT);
        #pragma unroll
        for (int q=0; q<COUT/4; ++q){
          float4 wv = wp[q];
          a0[4*q+0] = fmaf(wv.x, v0, a0[4*q+0]); a1[4*q+0] = fmaf(wv.x, v1, a1[4*q+0]);
          a0[4*q+1] = fmaf(wv.y, v0, a0[4*q+1]); a1[4*q+1] = fmaf(wv.y, v1, a1[4*q+1]);
          a0[4*q+2] = fmaf(wv.z, v0, a0[4*q+2]); a1[4*q+2] = fmaf(wv.z, v1, a1[4*q+2]);
          a0[4*q+3] = fmaf(wv.w, v0, a0[4*q+3]); a1[4*q+3] = fmaf(wv.w, v1, a1[4*q+3]);
        }
      }
    }
  }
  int oy = oy0+ty;
  float dtv = 0.f;
  if constexpr (MODE == 3) dtv = dtp[(nbase + n) >> 5];
  #pragma unroll
  for (int co=0; co<COUT; ++co){
    int i0 = ((n*COUT+co)*128+oy)*128 + ox0 + tx;
    int i1 = i0 + 16;
    if constexpr (MODE == 0){
      out[i0] = a0[co]; out[i1] = a1[co];
    } else if constexpr (MODE == 1){
      out[i0] = aux[co]*dsilu_(a0[co]);
      out[i1] = aux[co]*dsilu_(a1[co]);
    } else if constexpr (MODE == 2){
      out[i0] = a0[co]*dsilu_(aux[i0]);
      out[i1] = a1[co]*dsilu_(aux[i1]);
    } else {
      out[i0] = fmaf(dtv, a0[co], aux[i0]);
      out[i1] = fmaf(dtv, a1[co], aux[i1]);
    }
  }
}

// ---------------- forward rfft2, CT 16x8, pack trick, ping-pong LDS ---------
// out layout: Xf[img][wf*128 + k]; ortho scale with pack 0.5 -> 1/256 at end.
__global__ __launch_bounds__(1024) void k_fft_fwd(const float* __restrict__ xt,
                                                  float2* __restrict__ X){
  __shared__ float2 sA[8320];
  __shared__ float2 sB[8320];
  __shared__ float2 s_tw[128];
  __shared__ float2 s_t16[16];
  __shared__ float2 s_t8[8];
  int img = blockIdx.x, tid = threadIdx.x;
  if (tid < 128){ float sn,cs; sincosf((float)tid*0.04908738521234052f,&sn,&cs); s_tw[tid]=make_float2(cs,-sn); }
  if (tid < 16) { float sn,cs; sincosf((float)tid*0.39269908169872414f,&sn,&cs); s_t16[tid]=make_float2(cs,-sn); }
  if (tid < 8)  { float sn,cs; sincosf((float)tid*0.7853981633974483f ,&sn,&cs); s_t8[tid]=make_float2(cs,-sn); }
  const float* xp = xt + (size_t)img*16384;
  // pack rows: sA[hp*128+w] = x[2hp][w] + i x[2hp+1][w]
  #pragma unroll
  for (int it=0; it<8; ++it){
    int j = it*1024+tid; int hp=j>>7, w=j&127;
    sA[j] = make_float2(xp[hp*256 + w], xp[hp*256 + 128 + w]);
  }
  __syncthreads();
  // row stage 1: sB[hp][n2*16+k1] = (sum_n1 sA[hp][8n1+n2] W16^{n1k1}) W128^{n2k1}
  #pragma unroll
  for (int it=0; it<8; ++it){
    int i = it*1024+tid; int hp=i>>7, j=i&127, n2=j>>4, k1=j&15;
    float2 acc = make_float2(0.f,0.f);
    const float2* row = sA + hp*128 + n2;
    #pragma unroll
    for (int n1=0;n1<16;++n1) acc = cfma_(row[8*n1], s_t16[(n1*k1)&15], acc);
    sB[i] = cmul_(acc, s_tw[(n2*k1)&127]);
  }
  __syncthreads();
  // row stage 2: sA[hp][k1+16k2] = sum_n2 sB[hp][n2*16+k1] W8^{n2k2}
  #pragma unroll
  for (int it=0; it<8; ++it){
    int i = it*1024+tid; int hp=i>>7, k=i&127, k1=k&15, k2=k>>4;
    float2 acc = make_float2(0.f,0.f);
    const float2* u = sB + hp*128 + k1;
    #pragma unroll
    for (int n2=0;n2<8;++n2) acc = cfma_(u[16*n2], s_t8[(n2*k2)&7], acc);
    sA[i] = acc;
  }
  __syncthreads();
  // col stage 1 with on-the-fly unpack:
  // y[h][wf]: h=8n1+n2, even: Z1+conj(Z2); odd: (Z1-conj(Z2))/i (Z2 at 128-wf)
  #pragma unroll
  for (int it=0; it<9; ++it){
    int i = it*1024+tid;
    if (i < 8320){
      int wf=i>>7, j=i&127, n2=j>>4, k1=j&15;
      int j2 = (128-wf)&127;
      int par = n2&1;
      float2 acc = make_float2(0.f,0.f);
      #pragma unroll
      for (int n1=0;n1<16;++n1){
        int hp = 4*n1 + (n2>>1);
        float2 Z1 = sA[hp*128+wf];
        float2 Z2 = sA[hp*128+j2];
        float yr = par ? (Z1.y+Z2.y) : (Z1.x+Z2.x);
        float yi = par ? (Z2.x-Z1.x) : (Z1.y-Z2.y);
        acc = cfma_(make_float2(yr,yi), s_t16[(n1*k1)&15], acc);
      }
      sB[i] = cmul_(acc, s_tw[(n2*k1)&127]);
    }
    __syncthreads();
  }
  // col stage 2 + scaled store
  float2* Xp = X + (size_t)img*8320;
  #pragma unroll
  for (int it=0; it<9; ++it){
    int i = it*1024+tid;
    if (i < 8320){
      int wf=i>>7, k=i&127, k1=k&15, k2=k>>4;
      float2 acc = make_float2(0.f,0.f);
      const float2* u = sB + wf*128 + k1;
      #pragma unroll
      for (int n2=0;n2<8;++n2) acc = cfma_(u[16*n2], s_t8[(n2*k2)&7], acc);
      Xp[i] = make_float2(acc.x*(1.f/256.f), acc.y*(1.f/256.f));
    }
  }
}

// ---------------- fused projection+scan+projection+norms (in place) ---------
__global__ __launch_bounds__(256) void k_scan_fused(float2* __restrict__ X,
                                                    const float2* __restrict__ A2,
                                                    const float* __restrict__ gky,
                                                    const float* __restrict__ gkx,
                                                    const float* __restrict__ k2,
                                                    float* __restrict__ norms){
  int tid = blockIdx.x*256 + threadIdx.x;
  int cls = tid / 33280;
  int j   = tid - cls*33280;
  int b   = j / 8320;
  int r   = j - b*8320;           // wf*128 + k
  int lane0 = ((threadIdx.x & 63) == 0);

  if (cls == 0){
    float kyv = gky[r], kxv = gkx[r], ik2 = 1.f/k2[r];
    float2 a0 = A2[(b*8+0)*8320 + r];
    float2 a1 = A2[(b*8+1)*8320 + r];
    float h0r=0.f,h0i=0.f,h1r=0.f,h1i=0.f;
    for (int t=0; t<32; ++t){
      int base = ((b*32+t)*8)*8320 + r;
      float2 u = X[base];
      float2 v = X[base + 8320];
      float dr = (kyv*u.x + kxv*v.x)*ik2;
      float di = (kyv*u.y + kxv*v.y)*ik2;
      float uxr = u.x - kyv*dr, uxi = u.y - kyv*di;
      float vxr = v.x - kxv*dr, vxi = v.y - kxv*di;
      float ni = uxr*uxr + uxi*uxi + vxr*vxr + vxi*vxi;
      float n0r = a0.x*h0r - a0.y*h0i + uxr;
      float n0i = a0.x*h0i + a0.y*h0r + uxi;
      float n1r = a1.x*h1r - a1.y*h1i + vxr;
      float n1i = a1.x*h1i + a1.y*h1r + vxi;
      h0r=n0r; h0i=n0i; h1r=n1r; h1i=n1i;
      float er = (kyv*h0r + kxv*h1r)*ik2;
      float ei = (kyv*h0i + kxv*h1i)*ik2;
      float p0r = h0r - kyv*er, p0i = h0i - kyv*ei;
      float p1r = h1r - kxv*er, p1i = h1i - kxv*ei;
      float no = p0r*p0r + p0i*p0i + p1r*p1r + p1i*p1i;
      X[base]        = make_float2(p0r, p0i);
      X[base + 8320] = make_float2(p1r, p1i);
      #pragma unroll
      for (int off=32; off; off>>=1){ ni += __shfl_down(ni, off); no += __shfl_down(no, off); }
      if (lane0){ atomicAdd(&norms[(b*32+t)*2], ni); atomicAdd(&norms[(b*32+t)*2+1], no); }
    }
  } else {
    int c = cls + 1;
    float2 a = A2[(b*8+c)*8320 + r];
    float hr=0.f, hi=0.f;
    for (int t=0; t<32; ++t){
      int base = ((b*32+t)*8 + c)*8320 + r;
      float2 x = X[base];
      float ni = x.x*x.x + x.y*x.y;
      float nr = a.x*hr - a.y*hi + x.x;
      float nn = a.x*hi + a.y*hr + x.y;
      hr=nr; hi=nn;
      float no = hr*hr + hi*hi;
      X[base] = make_float2(hr, hi);
      #pragma unroll
      for (int off=32; off; off>>=1){ ni += __shfl_down(ni, off); no += __shfl_down(no, off); }
      if (lane0){ atomicAdd(&norms[(b*32+t)*2], ni); atomicAdd(&norms[(b*32+t)*2+1], no); }
    }
  }
}

// ---------------- inverse irfft2, CT 16x8, pack trick, ping-pong LDS --------
__global__ __launch_bounds__(1024) void k_fft_inv(const float2* __restrict__ X,
                                                  const float* __restrict__ norms,
                                                  float* __restrict__ out){
  __shared__ float2 sA[8320];
  __shared__ float2 sB[8320];
  __shared__ float2 s_tw[128];
  __shared__ float2 s_t16[16];
  __shared__ float2 s_t8[8];
  int img = blockIdx.x, tid = threadIdx.x;
  if (tid < 128){ float sn,cs; sincosf((float)tid*0.04908738521234052f,&sn,&cs); s_tw[tid]=make_float2(cs,sn); }
  if (tid < 16) { float sn,cs; sincosf((float)tid*0.39269908169872414f,&sn,&cs); s_t16[tid]=make_float2(cs,sn); }
  if (tid < 8)  { float sn,cs; sincosf((float)tid*0.7853981633974483f ,&sn,&cs); s_t8[tid]=make_float2(cs,sn); }
  const float2* Xp = X + (size_t)img*8320;
  #pragma unroll
  for (int it=0; it<9; ++it){ int i=it*1024+tid; if(i<8320) sA[i]=Xp[i]; }
  int bt = img >> 3;
  float scale = sqrtf(norms[bt*2]) / (sqrtf(norms[bt*2+1]) + 1e-6f) * (1.f/128.f);
  __syncthreads();
  // inv col stage 1 (input index k=8n1+n2): sA[wf][k] -> sB[wf][n2*16+k1]
  #pragma unroll
  for (int it=0; it<9; ++it){
    int i = it*1024+tid;
    if (i < 8320){
      int wf=i>>7, j=i&127, n2=j>>4, k1=j&15;
      float2 acc = make_float2(0.f,0.f);
      const float2* row = sA + wf*128 + n2;
      #pragma unroll
      for (int n1=0;n1<16;++n1) acc = cfma_(row[8*n1], s_t16[(n1*k1)&15], acc);
      sB[i] = cmul_(acc, s_tw[(n2*k1)&127]);
    }
    __syncthreads();
  }
  // inv col stage 2 -> y[wf][h] (scaled), natural layout sA[wf*128+h]
  #pragma unroll
  for (int it=0; it<9; ++it){
    int i = it*1024+tid;
    if (i < 8320){
      int wf=i>>7, h=i&127, k1=h&15, k2=h>>4;
      float2 acc = make_float2(0.f,0.f);
      const float2* u = sB + wf*128 + k1;
      #pragma unroll
      for (int n2=0;n2<8;++n2) acc = cfma_(u[16*n2], s_t8[(n2*k2)&7], acc);
      sA[i] = make_float2(acc.x*scale, acc.y*scale);
    }
    __syncthreads();
  }
  // inv row stage 1 with on-the-fly Hermitian pack (reads y[jj][2hp],y[jj][2hp+1]):
  // Z[wf'] = A+iB (wf'<=64, Im dropped at 0/64), conj(A)+i conj(B) (wf'>64)
  #pragma unroll
  for (int it=0; it<8; ++it){
    int i = it*1024+tid; int hp=i>>7, j=i&127, n2=j>>4, k1=j&15;
    float2 acc = make_float2(0.f,0.f);
    #pragma unroll
    for (int n1=0;n1<16;++n1){
      int wfp = 8*n1 + n2;
      int neg = wfp > 64;
      int jj = neg ? 128-wfp : wfp;
      float2 Av = sA[jj*128 + 2*hp];
      float2 Bv = sA[jj*128 + 2*hp + 1];
      if (jj == 0 || jj == 64){ Av.y = 0.f; Bv.y = 0.f; }
      float zr = neg ? (Av.x + Bv.y) : (Av.x - Bv.y);
      float zi = neg ? (Bv.x - Av.y) : (Av.y + Bv.x);
      acc = cfma_(make_float2(zr,zi), s_t16[(n1*k1)&15], acc);
    }
    sB[hp*128 + j] = cmul_(acc, s_tw[(n2*k1)&127]);
  }
  __syncthreads();
  // inv row stage 2 -> z[w] = x[2hp][w] + i x[2hp+1][w], store to global
  float* op = out + (size_t)img*16384;
  #pragma unroll
  for (int it=0; it<8; ++it){
    int i = it*1024+tid; int hp=i>>7, w=i&127, k1=w&15, k2=w>>4;
    float2 acc = make_float2(0.f,0.f);
    const float2* u = sB + hp*128 + k1;
    #pragma unroll
    for (int n2=0;n2<8;++n2) acc = cfma_(u[16*n2], s_t8[(n2*k2)&7], acc);
    op[hp*256 + w]       = acc.x;
    op[hp*256 + 128 + w] = acc.y;
  }
}

// ---------------------------------------------------------------------------
extern "C" void kernel_launch(void* const* d_in, const int* in_sizes, int n_in,
                              void* d_out, int out_size, void* d_ws, size_t ws_size,
                              hipStream_t stream) {
  const float* x_seq = (const float*)d_in[0];
  const float* dt    = (const float*)d_in[1];
  const float* pw1   = (const float*)d_in[2];
  const float* pb1   = (const float*)d_in[3];
  const float* pw2   = (const float*)d_in[4];
  const float* pb2   = (const float*)d_in[5];
  const float* c1w   = (const float*)d_in[6];
  const float* c1b   = (const float*)d_in[7];
  const float* c2w   = (const float*)d_in[8];
  const float* c2b   = (const float*)d_in[9];
  const float* c3w   = (const float*)d_in[10];
  float* out = (float*)d_out;
  float* ws  = (float*)d_ws;

  const size_t XFH_F  = 17039360;                 // 65*128*1024 float2 in floats
  const size_t TAIL_F = 532480 + 3*8320 + 16 + 256;
  size_t avail_f = ws_size / 4;

  int chunk = 16;
  for (int c = 128; c >= 16; c >>= 1){
    size_t scratch = (size_t)3*c*262144;
    size_t R = scratch > XFH_F ? scratch : XFH_F;
    if (R + TAIL_F <= avail_f){ chunk = c; break; }
  }
  size_t Rsz = (size_t)3*chunk*262144; if (Rsz < XFH_F) Rsz = XFH_F;

  float*  Aa   = ws + Rsz;
  float*  GKY  = Aa + 532480;
  float*  GKX  = GKY + 8320;
  float*  K2   = GKX + 8320;
  float*  S3   = K2  + 8320;
  float*  NORMS= S3  + 16;

  float2* XFH = (float2*)ws;
  float2* A2  = (float2*)Aa;

  float* CZ1  = ws;
  float* CGZ2 = ws + (size_t)chunk*262144;
  float* CGZ1 = ws + (size_t)2*chunk*262144;

  k_setup_misc<<<1, 256, 0, stream>>>(c3w, S3, NORMS);
  k_setup_grid<<<33, 256, 0, stream>>>(dt, pw1, pb1, pw2, pb2, GKY, GKX, K2, A2);

  dim3 cb(16,16), cg(4,8,chunk);
  for (int n0 = 0; n0 < 128; n0 += chunk){
    const float* xin = x_seq + (size_t)n0*8*16384;
    float*       xtp = out   + (size_t)n0*8*16384;   // XT staged in d_out
    k_conv<8,16,0><<<cg, cb, 0, stream>>>(xin, c1w, c1b, nullptr, nullptr, CZ1, n0);
    k_conv<16,16,1><<<cg, cb, 0, stream>>>(CZ1, c2w, c2b, S3, nullptr, CGZ2, n0);
    k_conv<16,16,2><<<cg, cb, 0, stream>>>(CGZ2, c2w, nullptr, CZ1, nullptr, CGZ1, n0);
    k_conv<16,8,3><<<cg, cb, 0, stream>>>(CGZ1, c1w, nullptr, xin, dt, xtp, n0);
  }

  k_fft_fwd<<<1024, 1024, 0, stream>>>(out, XFH);
  k_scan_fused<<<910, 256, 0, stream>>>(XFH, A2, GKY, GKX, K2, NORMS);
  k_fft_inv<<<1024, 1024, 0, stream>>>(XFH, NORMS, out);
}

// Round 5
// 1301.515 us; speedup vs baseline: 2.1465x; 1.3194x over previous
//
#include <hip/hip_runtime.h>
#include <math.h>

// ---------------------------------------------------------------------------
// UniPhyFluidScan. B=4 T=32 C=8 H=128 W=128, Wf=65. 128 conv imgs, 1024 spectra.
//
// FFTs: 2-stage Cooley-Tukey (N=128=16x8), per-image workgroup (1024 thr),
// ping-pong LDS buffers. Row r2c/c2r passes use the pack trick.
// Scan stage (round-5 restructure): k_proj (project ch0/1 + pair-norm) and
// k_normS (singles norm) run pre- and post-scan; k_scan is a pure streaming
// recurrence (no shfl/atomics in the serial loop -- round-4 lesson: the fused
// version was latency-bound at 1.2% VALU).
// Convs: analytic gradient chain (4 direct 3x3 passes), chunked by ws_size.
//
// ws layout (floats): [ R = max(conv scratch, XFH=17,039,360) | A 532,480 |
//                       GKY 8320 | GKX 8320 | K2 8320 | S3 16 | NORMS 256 ]
// ---------------------------------------------------------------------------

#define CC 8

__device__ __forceinline__ float sig_(float x){ return 1.f/(1.f+expf(-x)); }
__device__ __forceinline__ float dsilu_(float x){ float s = sig_(x); return s*(1.f + x*(1.f-s)); }

__device__ __forceinline__ float2 cmul_(float2 a, float2 t){
  return make_float2(fmaf(a.x,t.x,-a.y*t.y), fmaf(a.x,t.y, a.y*t.x));
}
__device__ __forceinline__ float2 cfma_(float2 a, float2 t, float2 acc){
  acc.x = fmaf(a.x,t.x,fmaf(-a.y,t.y,acc.x));
  acc.y = fmaf(a.x,t.y,fmaf( a.y,t.x,acc.y));
  return acc;
}

// ---------------- setup ----------------------------------------------------
__global__ void k_setup_misc(const float* __restrict__ c3w,
                             float* __restrict__ s3, float* __restrict__ norms){
  int t = threadIdx.x;
  if (t < 16){
    float s = 0.f;
    for (int co=0; co<8; ++co) s += c3w[co*16 + t];
    s3[t] = s;
  }
  norms[t] = 0.f;
}

// one thread per (wf,k): tid = wf*128 + k
__global__ void k_setup_grid(const float* __restrict__ dt, const float* __restrict__ w1,
                             const float* __restrict__ b1, const float* __restrict__ w2,
                             const float* __restrict__ b2,
                             float* __restrict__ gky_a, float* __restrict__ gkx_a,
                             float* __restrict__ k2_a, float2* __restrict__ A){
  int tid = blockIdx.x*blockDim.x + threadIdx.x;
  if (tid >= 65*128) return;
  int wf = tid >> 7, k = tid & 127;
  float ky = (float)(k < 64 ? k : k-128) * (1.f/128.f);
  float kx = (float)wf * (1.f/128.f);
  gky_a[tid] = ky; gkx_a[tid] = kx;
  float k2 = ky*ky + kx*kx;
  k2_a[tid] = (tid==0) ? 1.f : k2;
  float kphys = sqrtf(ky*ky + kx*kx);
  float omega[CC];
  #pragma unroll
  for (int c=0;c<CC;++c) omega[c] = b2[c];
  for (int j=0;j<64;++j){
    float hp = ky*w1[j] + kx*w1[64+j] + b1[j];
    float hv = hp * sig_(hp);
    #pragma unroll
    for (int c=0;c<CC;++c) omega[c] = fmaf(hv, w2[j*CC + c], omega[c]);
  }
  #pragma unroll
  for (int c=0;c<CC;++c) omega[c] += kphys;
  for (int b=0;b<4;++b){
    float d = dt[b];
    #pragma unroll
    for (int c=0;c<CC;++c){
      float ph = omega[c]*d;
      float sn, cs; sincosf(ph, &sn, &cs);
      A[(b*8+c)*8320 + tid] = make_float2(cs, sn);
    }
  }
}

// ---------------- conv family ----------------------------------------------
// MODE 0: z1 = conv1(x)+b1
// MODE 1: gz2 = s3*silu'(conv2(silu(in))+b2)
// MODE 2: gz1 = convT2(in) * silu'(aux)
// MODE 3: XT  = aux + dt[(nbase+n)/32]*convT1(in)
template<int CIN, int COUT, int MODE>
__global__ __launch_bounds__(256) void k_conv(const float* __restrict__ in,
                                              const float* __restrict__ wsrc,
                                              const float* __restrict__ bias,
                                              const float* __restrict__ aux,
                                              const float* __restrict__ dtp,
                                              float* __restrict__ out,
                                              int nbase){
  __shared__ float s_in[CIN*18*34];
  __shared__ __align__(16) float s_w[CIN*9*COUT];
  int n = blockIdx.z;
  int ox0 = blockIdx.x*32, oy0 = blockIdx.y*16;
  int tx = threadIdx.x, ty = threadIdx.y;
  int tid = ty*16 + tx;

  for (int i=tid; i<CIN*9*COUT; i+=256){
    int co = i % COUT; int r = i / COUT;   // r = ci*9+k
    float wv;
    if constexpr (MODE <= 1){
      wv = wsrc[co*(CIN*9) + r];
    } else {
      int ci = r/9, k = r - ci*9, ky = k/3, kx = k - ky*3;
      wv = wsrc[(ci*COUT+co)*9 + (2-ky)*3 + (2-kx)];
    }
    s_w[i] = wv;
  }
  const float* ip = in + (size_t)n*CIN*16384;
  for (int i=tid; i<CIN*612; i+=256){
    int ci = i/612; int p = i - ci*612; int py = p/34, px = p - py*34;
    int gy = oy0 + py - 1, gx = ox0 + px - 1;
    float v = 0.f;
    if ((unsigned)gy < 128u && (unsigned)gx < 128u) v = ip[(ci*128+gy)*128+gx];
    if constexpr (MODE == 1) v = v * sig_(v);
    s_in[i] = v;
  }
  __syncthreads();

  float a0[COUT], a1[COUT];
  #pragma unroll
  for (int co=0; co<COUT; ++co){
    float b = 0.f;
    if constexpr (MODE <= 1) b = bias[co];
    a0[co] = b; a1[co] = b;
  }
  for (int ci=0; ci<CIN; ++ci){
    const float* si = s_in + ci*612;
    #pragma unroll
    for (int ky=0; ky<3; ++ky){
      #pragma unroll
      for (int kx=0; kx<3; ++kx){
        float v0 = si[(ty+ky)*34 + tx+kx];
        float v1 = si[(ty+ky)*34 + tx+16+kx];
        const float4* wp = (const float4*)(s_w + (ci*9 + ky*3+kx)*COUT);
        #pragma unroll
        for (int q=0; q<COUT/4; ++q){
          float4 wv = wp[q];
          a0[4*q+0] = fmaf(wv.x, v0, a0[4*q+0]); a1[4*q+0] = fmaf(wv.x, v1, a1[4*q+0]);
          a0[4*q+1] = fmaf(wv.y, v0, a0[4*q+1]); a1[4*q+1] = fmaf(wv.y, v1, a1[4*q+1]);
          a0[4*q+2] = fmaf(wv.z, v0, a0[4*q+2]); a1[4*q+2] = fmaf(wv.z, v1, a1[4*q+2]);
          a0[4*q+3] = fmaf(wv.w, v0, a0[4*q+3]); a1[4*q+3] = fmaf(wv.w, v1, a1[4*q+3]);
        }
      }
    }
  }
  int oy = oy0+ty;
  float dtv = 0.f;
  if constexpr (MODE == 3) dtv = dtp[(nbase + n) >> 5];
  #pragma unroll
  for (int co=0; co<COUT; ++co){
    int i0 = ((n*COUT+co)*128+oy)*128 + ox0 + tx;
    int i1 = i0 + 16;
    if constexpr (MODE == 0){
      out[i0] = a0[co]; out[i1] = a1[co];
    } else if constexpr (MODE == 1){
      out[i0] = aux[co]*dsilu_(a0[co]);
      out[i1] = aux[co]*dsilu_(a1[co]);
    } else if constexpr (MODE == 2){
      out[i0] = a0[co]*dsilu_(aux[i0]);
      out[i1] = a1[co]*dsilu_(aux[i1]);
    } else {
      out[i0] = fmaf(dtv, a0[co], aux[i0]);
      out[i1] = fmaf(dtv, a1[co], aux[i1]);
    }
  }
}

// ---------------- forward rfft2, CT 16x8, pack trick, ping-pong LDS ---------
// out layout: Xf[img][wf*128 + k]; ortho scale with pack 0.5 -> 1/256 at end.
__global__ __launch_bounds__(1024) void k_fft_fwd(const float* __restrict__ xt,
                                                  float2* __restrict__ X){
  __shared__ float2 sA[8320];
  __shared__ float2 sB[8320];
  __shared__ float2 s_tw[128];
  __shared__ float2 s_t16[16];
  __shared__ float2 s_t8[8];
  int img = blockIdx.x, tid = threadIdx.x;
  if (tid < 128){ float sn,cs; sincosf((float)tid*0.04908738521234052f,&sn,&cs); s_tw[tid]=make_float2(cs,-sn); }
  if (tid < 16) { float sn,cs; sincosf((float)tid*0.39269908169872414f,&sn,&cs); s_t16[tid]=make_float2(cs,-sn); }
  if (tid < 8)  { float sn,cs; sincosf((float)tid*0.7853981633974483f ,&sn,&cs); s_t8[tid]=make_float2(cs,-sn); }
  const float* xp = xt + (size_t)img*16384;
  // pack rows: sA[hp*128+w] = x[2hp][w] + i x[2hp+1][w]
  #pragma unroll
  for (int it=0; it<8; ++it){
    int j = it*1024+tid; int hp=j>>7, w=j&127;
    sA[j] = make_float2(xp[hp*256 + w], xp[hp*256 + 128 + w]);
  }
  __syncthreads();
  // row stage 1
  #pragma unroll
  for (int it=0; it<8; ++it){
    int i = it*1024+tid; int hp=i>>7, j=i&127, n2=j>>4, k1=j&15;
    float2 acc = make_float2(0.f,0.f);
    const float2* row = sA + hp*128 + n2;
    #pragma unroll
    for (int n1=0;n1<16;++n1) acc = cfma_(row[8*n1], s_t16[(n1*k1)&15], acc);
    sB[i] = cmul_(acc, s_tw[(n2*k1)&127]);
  }
  __syncthreads();
  // row stage 2
  #pragma unroll
  for (int it=0; it<8; ++it){
    int i = it*1024+tid; int hp=i>>7, k=i&127, k1=k&15, k2=k>>4;
    float2 acc = make_float2(0.f,0.f);
    const float2* u = sB + hp*128 + k1;
    #pragma unroll
    for (int n2=0;n2<8;++n2) acc = cfma_(u[16*n2], s_t8[(n2*k2)&7], acc);
    sA[i] = acc;
  }
  __syncthreads();
  // col stage 1 with on-the-fly unpack
  #pragma unroll
  for (int it=0; it<9; ++it){
    int i = it*1024+tid;
    if (i < 8320){
      int wf=i>>7, j=i&127, n2=j>>4, k1=j&15;
      int j2 = (128-wf)&127;
      int par = n2&1;
      float2 acc = make_float2(0.f,0.f);
      #pragma unroll
      for (int n1=0;n1<16;++n1){
        int hp = 4*n1 + (n2>>1);
        float2 Z1 = sA[hp*128+wf];
        float2 Z2 = sA[hp*128+j2];
        float yr = par ? (Z1.y+Z2.y) : (Z1.x+Z2.x);
        float yi = par ? (Z2.x-Z1.x) : (Z1.y-Z2.y);
        acc = cfma_(make_float2(yr,yi), s_t16[(n1*k1)&15], acc);
      }
      sB[i] = cmul_(acc, s_tw[(n2*k1)&127]);
    }
    __syncthreads();
  }
  // col stage 2 + scaled store
  float2* Xp = X + (size_t)img*8320;
  #pragma unroll
  for (int it=0; it<9; ++it){
    int i = it*1024+tid;
    if (i < 8320){
      int wf=i>>7, k=i&127, k1=k&15, k2=k>>4;
      float2 acc = make_float2(0.f,0.f);
      const float2* u = sB + wf*128 + k1;
      #pragma unroll
      for (int n2=0;n2<8;++n2) acc = cfma_(u[16*n2], s_t8[(n2*k2)&7], acc);
      Xp[i] = make_float2(acc.x*(1.f/256.f), acc.y*(1.f/256.f));
    }
  }
}

// ---------------- scan stage (split kernels) --------------------------------
// k_proj: project ch0/1 in place for one (b,t) image; accumulate pair-norm
// into norms[bt*2+ofs]. Grid (128, 33), 256 thr.
__global__ __launch_bounds__(256) void k_proj(float2* __restrict__ X,
                                              const float* __restrict__ gky,
                                              const float* __restrict__ gkx,
                                              const float* __restrict__ k2,
                                              float* __restrict__ norms, int ofs){
  int bt = blockIdx.x;
  int r = blockIdx.y*256 + threadIdx.x;
  float acc = 0.f;
  if (r < 8320){
    size_t base = (size_t)bt*66560 + r;
    float2 u = X[base], v = X[base+8320];
    float ky=gky[r], kx=gkx[r], ik2=1.f/k2[r];
    float dr=(ky*u.x+kx*v.x)*ik2, di=(ky*u.y+kx*v.y)*ik2;
    u.x-=ky*dr; u.y-=ky*di; v.x-=kx*dr; v.y-=kx*di;
    X[base]=u; X[base+8320]=v;
    acc = u.x*u.x+u.y*u.y+v.x*v.x+v.y*v.y;
  }
  #pragma unroll
  for (int off=32; off; off>>=1) acc += __shfl_down(acc, off);
  __shared__ float red[4];
  int wid=threadIdx.x>>6, lane=threadIdx.x&63;
  if (lane==0) red[wid]=acc;
  __syncthreads();
  if (threadIdx.x==0) atomicAdd(&norms[bt*2+ofs], red[0]+red[1]+red[2]+red[3]);
}

// k_normS: |.|^2 over channels 2..7 of one (b,t). Grid (128, 25), 256 thr.
__global__ __launch_bounds__(256) void k_normS(const float2* __restrict__ X,
                                               float* __restrict__ norms, int ofs){
  int bt = blockIdx.x;
  int e0 = 16640 + blockIdx.y*2048 + threadIdx.x;
  float acc = 0.f;
  #pragma unroll
  for (int i=0; i<8; ++i){
    int e = e0 + i*256;
    if (e < 66560){
      float2 x = X[(size_t)bt*66560 + e];
      acc = fmaf(x.x,x.x,fmaf(x.y,x.y,acc));
    }
  }
  #pragma unroll
  for (int off=32; off; off>>=1) acc += __shfl_down(acc, off);
  __shared__ float red[4];
  int wid=threadIdx.x>>6, lane=threadIdx.x&63;
  if (lane==0) red[wid]=acc;
  __syncthreads();
  if (threadIdx.x==0) atomicAdd(&norms[bt*2+ofs], red[0]+red[1]+red[2]+red[3]);
}

// k_scan: pure streaming recurrence h[t] = a*h[t-1] + x[t], in place.
// chain id = b*66560 + c*8320 + r; per-t stride 66560 float2.
__global__ __launch_bounds__(256) void k_scan(float2* __restrict__ X,
                                              const float2* __restrict__ A2){
  int tid = blockIdx.x*256 + threadIdx.x;
  if (tid >= 266240) return;
  int b = tid/66560, cr = tid - b*66560;
  float2 a = A2[tid];
  float2* p = X + (size_t)b*2129920 + cr;
  float hr=0.f, hi=0.f;
  #pragma unroll
  for (int t=0; t<32; ++t){
    float2 x = p[(size_t)t*66560];
    float nr = fmaf(a.x,hr,fmaf(-a.y,hi,x.x));
    float nn = fmaf(a.x,hi,fmaf( a.y,hr,x.y));
    hr=nr; hi=nn;
    p[(size_t)t*66560] = make_float2(hr,hi);
  }
}

// ---------------- inverse irfft2, CT 16x8, pack trick, ping-pong LDS --------
__global__ __launch_bounds__(1024) void k_fft_inv(const float2* __restrict__ X,
                                                  const float* __restrict__ norms,
                                                  float* __restrict__ out){
  __shared__ float2 sA[8320];
  __shared__ float2 sB[8320];
  __shared__ float2 s_tw[128];
  __shared__ float2 s_t16[16];
  __shared__ float2 s_t8[8];
  int img = blockIdx.x, tid = threadIdx.x;
  if (tid < 128){ float sn,cs; sincosf((float)tid*0.04908738521234052f,&sn,&cs); s_tw[tid]=make_float2(cs,sn); }
  if (tid < 16) { float sn,cs; sincosf((float)tid*0.39269908169872414f,&sn,&cs); s_t16[tid]=make_float2(cs,sn); }
  if (tid < 8)  { float sn,cs; sincosf((float)tid*0.7853981633974483f ,&sn,&cs); s_t8[tid]=make_float2(cs,sn); }
  const float2* Xp = X + (size_t)img*8320;
  #pragma unroll
  for (int it=0; it<9; ++it){ int i=it*1024+tid; if(i<8320) sA[i]=Xp[i]; }
  int bt = img >> 3;
  float scale = sqrtf(norms[bt*2]) / (sqrtf(norms[bt*2+1]) + 1e-6f) * (1.f/128.f);
  __syncthreads();
  // inv col stage 1
  #pragma unroll
  for (int it=0; it<9; ++it){
    int i = it*1024+tid;
    if (i < 8320){
      int wf=i>>7, j=i&127, n2=j>>4, k1=j&15;
      float2 acc = make_float2(0.f,0.f);
      const float2* row = sA + wf*128 + n2;
      #pragma unroll
      for (int n1=0;n1<16;++n1) acc = cfma_(row[8*n1], s_t16[(n1*k1)&15], acc);
      sB[i] = cmul_(acc, s_tw[(n2*k1)&127]);
    }
    __syncthreads();
  }
  // inv col stage 2 -> y[wf][h] (scaled)
  #pragma unroll
  for (int it=0; it<9; ++it){
    int i = it*1024+tid;
    if (i < 8320){
      int wf=i>>7, h=i&127, k1=h&15, k2=h>>4;
      float2 acc = make_float2(0.f,0.f);
      const float2* u = sB + wf*128 + k1;
      #pragma unroll
      for (int n2=0;n2<8;++n2) acc = cfma_(u[16*n2], s_t8[(n2*k2)&7], acc);
      sA[i] = make_float2(acc.x*scale, acc.y*scale);
    }
    __syncthreads();
  }
  // inv row stage 1 with on-the-fly Hermitian pack
  #pragma unroll
  for (int it=0; it<8; ++it){
    int i = it*1024+tid; int hp=i>>7, j=i&127, n2=j>>4, k1=j&15;
    float2 acc = make_float2(0.f,0.f);
    #pragma unroll
    for (int n1=0;n1<16;++n1){
      int wfp = 8*n1 + n2;
      int neg = wfp > 64;
      int jj = neg ? 128-wfp : wfp;
      float2 Av = sA[jj*128 + 2*hp];
      float2 Bv = sA[jj*128 + 2*hp + 1];
      if (jj == 0 || jj == 64){ Av.y = 0.f; Bv.y = 0.f; }
      float zr = neg ? (Av.x + Bv.y) : (Av.x - Bv.y);
      float zi = neg ? (Bv.x - Av.y) : (Av.y + Bv.x);
      acc = cfma_(make_float2(zr,zi), s_t16[(n1*k1)&15], acc);
    }
    sB[hp*128 + j] = cmul_(acc, s_tw[(n2*k1)&127]);
  }
  __syncthreads();
  // inv row stage 2 -> store
  float* op = out + (size_t)img*16384;
  #pragma unroll
  for (int it=0; it<8; ++it){
    int i = it*1024+tid; int hp=i>>7, w=i&127, k1=w&15, k2=w>>4;
    float2 acc = make_float2(0.f,0.f);
    const float2* u = sB + hp*128 + k1;
    #pragma unroll
    for (int n2=0;n2<8;++n2) acc = cfma_(u[16*n2], s_t8[(n2*k2)&7], acc);
    op[hp*256 + w]       = acc.x;
    op[hp*256 + 128 + w] = acc.y;
  }
}

// ---------------------------------------------------------------------------
extern "C" void kernel_launch(void* const* d_in, const int* in_sizes, int n_in,
                              void* d_out, int out_size, void* d_ws, size_t ws_size,
                              hipStream_t stream) {
  const float* x_seq = (const float*)d_in[0];
  const float* dt    = (const float*)d_in[1];
  const float* pw1   = (const float*)d_in[2];
  const float* pb1   = (const float*)d_in[3];
  const float* pw2   = (const float*)d_in[4];
  const float* pb2   = (const float*)d_in[5];
  const float* c1w   = (const float*)d_in[6];
  const float* c1b   = (const float*)d_in[7];
  const float* c2w   = (const float*)d_in[8];
  const float* c2b   = (const float*)d_in[9];
  const float* c3w   = (const float*)d_in[10];
  float* out = (float*)d_out;
  float* ws  = (float*)d_ws;

  const size_t XFH_F  = 17039360;                 // 65*128*1024 float2 in floats
  const size_t TAIL_F = 532480 + 3*8320 + 16 + 256;
  size_t avail_f = ws_size / 4;

  int chunk = 16;
  for (int c = 128; c >= 16; c >>= 1){
    size_t scratch = (size_t)3*c*262144;
    size_t R = scratch > XFH_F ? scratch : XFH_F;
    if (R + TAIL_F <= avail_f){ chunk = c; break; }
  }
  size_t Rsz = (size_t)3*chunk*262144; if (Rsz < XFH_F) Rsz = XFH_F;

  float*  Aa   = ws + Rsz;
  float*  GKY  = Aa + 532480;
  float*  GKX  = GKY + 8320;
  float*  K2   = GKX + 8320;
  float*  S3   = K2  + 8320;
  float*  NORMS= S3  + 16;

  float2* XFH = (float2*)ws;
  float2* A2  = (float2*)Aa;

  float* CZ1  = ws;
  float* CGZ2 = ws + (size_t)chunk*262144;
  float* CGZ1 = ws + (size_t)2*chunk*262144;

  k_setup_misc<<<1, 256, 0, stream>>>(c3w, S3, NORMS);
  k_setup_grid<<<33, 256, 0, stream>>>(dt, pw1, pb1, pw2, pb2, GKY, GKX, K2, A2);

  dim3 cb(16,16), cg(4,8,chunk);
  for (int n0 = 0; n0 < 128; n0 += chunk){
    const float* xin = x_seq + (size_t)n0*8*16384;
    float*       xtp = out   + (size_t)n0*8*16384;   // XT staged in d_out
    k_conv<8,16,0><<<cg, cb, 0, stream>>>(xin, c1w, c1b, nullptr, nullptr, CZ1, n0);
    k_conv<16,16,1><<<cg, cb, 0, stream>>>(CZ1, c2w, c2b, S3, nullptr, CGZ2, n0);
    k_conv<16,16,2><<<cg, cb, 0, stream>>>(CGZ2, c2w, nullptr, CZ1, nullptr, CGZ1, n0);
    k_conv<16,8,3><<<cg, cb, 0, stream>>>(CGZ1, c1w, nullptr, xin, dt, xtp, n0);
  }

  k_fft_fwd<<<1024, 1024, 0, stream>>>(out, XFH);

  k_proj <<<dim3(128,33), 256, 0, stream>>>((float2*)XFH, GKY, GKX, K2, NORMS, 0);
  k_normS<<<dim3(128,25), 256, 0, stream>>>((const float2*)XFH, NORMS, 0);
  k_scan <<<1040, 256, 0, stream>>>((float2*)XFH, A2);
  k_proj <<<dim3(128,33), 256, 0, stream>>>((float2*)XFH, GKY, GKX, K2, NORMS, 1);
  k_normS<<<dim3(128,25), 256, 0, stream>>>((const float2*)XFH, NORMS, 1);

  k_fft_inv<<<1024, 1024, 0, stream>>>(XFH, NORMS, out);
}

// Round 7
// 1270.163 us; speedup vs baseline: 2.1995x; 1.0247x over previous
//
#include <hip/hip_runtime.h>
#include <math.h>

// ---------------------------------------------------------------------------
// UniPhyFluidScan. B=4 T=32 C=8 H=128 W=128, Wf=65. 128 conv imgs, 1024 spectra.
//
// FFTs: 2-stage Cooley-Tukey (N=128=16x8), per-image workgroup (1024 thr),
// ping-pong LDS buffers; barriers only between stages (round-6: hoisted the
// per-iteration barriers out of col-stage loops).
// Convs: block (32,8) so each wave = 2 rows x 32 cols -> 2 lanes/bank max on
// the 34-wide s_in tile (round-6 fix; (16,16) waves spanned 4 rows = 4-way
// conflicts, 4.7e6/dispatch).
// Scan stage: k_proj / k_normS / pure-streaming k_scan (round-5 structure).
//
// ws layout (floats): [ R = max(conv scratch, XFH=17,039,360) | A 532,480 |
//                       GKY 8320 | GKX 8320 | K2 8320 | S3 16 | NORMS 256 ]
// ---------------------------------------------------------------------------

#define CC 8

__device__ __forceinline__ float sig_(float x){ return 1.f/(1.f+expf(-x)); }
__device__ __forceinline__ float dsilu_(float x){ float s = sig_(x); return s*(1.f + x*(1.f-s)); }

__device__ __forceinline__ float2 cmul_(float2 a, float2 t){
  return make_float2(fmaf(a.x,t.x,-a.y*t.y), fmaf(a.x,t.y, a.y*t.x));
}
__device__ __forceinline__ float2 cfma_(float2 a, float2 t, float2 acc){
  acc.x = fmaf(a.x,t.x,fmaf(-a.y,t.y,acc.x));
  acc.y = fmaf(a.x,t.y,fmaf( a.y,t.x,acc.y));
  return acc;
}

// ---------------- setup ----------------------------------------------------
__global__ void k_setup_misc(const float* __restrict__ c3w,
                             float* __restrict__ s3, float* __restrict__ norms){
  int t = threadIdx.x;
  if (t < 16){
    float s = 0.f;
    for (int co=0; co<8; ++co) s += c3w[co*16 + t];
    s3[t] = s;
  }
  norms[t] = 0.f;
}

// one thread per (wf,k): tid = wf*128 + k
__global__ void k_setup_grid(const float* __restrict__ dt, const float* __restrict__ w1,
                             const float* __restrict__ b1, const float* __restrict__ w2,
                             const float* __restrict__ b2,
                             float* __restrict__ gky_a, float* __restrict__ gkx_a,
                             float* __restrict__ k2_a, float2* __restrict__ A){
  int tid = blockIdx.x*blockDim.x + threadIdx.x;
  if (tid >= 65*128) return;
  int wf = tid >> 7, k = tid & 127;
  float ky = (float)(k < 64 ? k : k-128) * (1.f/128.f);
  float kx = (float)wf * (1.f/128.f);
  gky_a[tid] = ky; gkx_a[tid] = kx;
  float k2 = ky*ky + kx*kx;
  k2_a[tid] = (tid==0) ? 1.f : k2;
  float kphys = sqrtf(ky*ky + kx*kx);
  float omega[CC];
  #pragma unroll
  for (int c=0;c<CC;++c) omega[c] = b2[c];
  for (int j=0;j<64;++j){
    float hp = ky*w1[j] + kx*w1[64+j] + b1[j];
    float hv = hp * sig_(hp);
    #pragma unroll
    for (int c=0;c<CC;++c) omega[c] = fmaf(hv, w2[j*CC + c], omega[c]);
  }
  #pragma unroll
  for (int c=0;c<CC;++c) omega[c] += kphys;
  for (int b=0;b<4;++b){
    float d = dt[b];
    #pragma unroll
    for (int c=0;c<CC;++c){
      float ph = omega[c]*d;
      float sn, cs; sincosf(ph, &sn, &cs);
      A[(b*8+c)*8320 + tid] = make_float2(cs, sn);
    }
  }
}

// ---------------- conv family ----------------------------------------------
// Tile 16 rows x 32 cols, block (32,8), 2 px/thread at rows ty and ty+8.
// MODE 0: z1 = conv1(x)+b1
// MODE 1: gz2 = s3*silu'(conv2(silu(in))+b2)
// MODE 2: gz1 = convT2(in) * silu'(aux)
// MODE 3: XT  = aux + dt[(nbase+n)/32]*convT1(in)
template<int CIN, int COUT, int MODE>
__global__ __launch_bounds__(256) void k_conv(const float* __restrict__ in,
                                              const float* __restrict__ wsrc,
                                              const float* __restrict__ bias,
                                              const float* __restrict__ aux,
                                              const float* __restrict__ dtp,
                                              float* __restrict__ out,
                                              int nbase){
  __shared__ float s_in[CIN*18*34];
  __shared__ __align__(16) float s_w[CIN*9*COUT];
  int n = blockIdx.z;
  int ox0 = blockIdx.x*32, oy0 = blockIdx.y*16;
  int tx = threadIdx.x, ty = threadIdx.y;       // (32,8)
  int tid = ty*32 + tx;

  for (int i=tid; i<CIN*9*COUT; i+=256){
    int co = i % COUT; int r = i / COUT;   // r = ci*9+k
    float wv;
    if constexpr (MODE <= 1){
      wv = wsrc[co*(CIN*9) + r];
    } else {
      int ci = r/9, k = r - ci*9, ky = k/3, kx = k - ky*3;
      wv = wsrc[(ci*COUT+co)*9 + (2-ky)*3 + (2-kx)];
    }
    s_w[i] = wv;
  }
  const float* ip = in + (size_t)n*CIN*16384;
  for (int i=tid; i<CIN*612; i+=256){
    int ci = i/612; int p = i - ci*612; int py = p/34, px = p - py*34;
    int gy = oy0 + py - 1, gx = ox0 + px - 1;
    float v = 0.f;
    if ((unsigned)gy < 128u && (unsigned)gx < 128u) v = ip[(ci*128+gy)*128+gx];
    if constexpr (MODE == 1) v = v * sig_(v);
    s_in[i] = v;
  }
  __syncthreads();

  float a0[COUT], a1[COUT];
  #pragma unroll
  for (int co=0; co<COUT; ++co){
    float b = 0.f;
    if constexpr (MODE <= 1) b = bias[co];
    a0[co] = b; a1[co] = b;
  }
  for (int ci=0; ci<CIN; ++ci){
    const float* si = s_in + ci*612;
    #pragma unroll
    for (int ky=0; ky<3; ++ky){
      #pragma unroll
      for (int kx=0; kx<3; ++kx){
        float v0 = si[(ty+ky)*34 + tx+kx];
        float v1 = si[(ty+8+ky)*34 + tx+kx];
        const float4* wp = (const float4*)(s_w + (ci*9 + ky*3+kx)*COUT);
        #pragma unroll
        for (int q=0; q<COUT/4; ++q){
          float4 wv = wp[q];
          a0[4*q+0] = fmaf(wv.x, v0, a0[4*q+0]); a1[4*q+0] = fmaf(wv.x, v1, a1[4*q+0]);
          a0[4*q+1] = fmaf(wv.y, v0, a0[4*q+1]); a1[4*q+1] = fmaf(wv.y, v1, a1[4*q+1]);
          a0[4*q+2] = fmaf(wv.z, v0, a0[4*q+2]); a1[4*q+2] = fmaf(wv.z, v1, a1[4*q+2]);
          a0[4*q+3] = fmaf(wv.w, v0, a0[4*q+3]); a1[4*q+3] = fmaf(wv.w, v1, a1[4*q+3]);
        }
      }
    }
  }
  int oy = oy0+ty;
  float dtv = 0.f;
  if constexpr (MODE == 3) dtv = dtp[(nbase + n) >> 5];
  #pragma unroll
  for (int co=0; co<COUT; ++co){
    int i0 = ((n*COUT+co)*128+oy)*128 + ox0 + tx;
    int i1 = i0 + 8*128;
    if constexpr (MODE == 0){
      out[i0] = a0[co]; out[i1] = a1[co];
    } else if constexpr (MODE == 1){
      out[i0] = aux[co]*dsilu_(a0[co]);
      out[i1] = aux[co]*dsilu_(a1[co]);
    } else if constexpr (MODE == 2){
      out[i0] = a0[co]*dsilu_(aux[i0]);
      out[i1] = a1[co]*dsilu_(aux[i1]);
    } else {
      out[i0] = fmaf(dtv, a0[co], aux[i0]);
      out[i1] = fmaf(dtv, a1[co], aux[i1]);
    }
  }
}

// ---------------- forward rfft2, CT 16x8, pack trick, ping-pong LDS ---------
// out layout: Xf[img][wf*128 + k]; ortho scale with pack 0.5 -> 1/256 at end.
__global__ __launch_bounds__(1024) void k_fft_fwd(const float* __restrict__ xt,
                                                  float2* __restrict__ X){
  __shared__ float2 sA[8320];
  __shared__ float2 sB[8320];
  __shared__ float2 s_tw[128];
  __shared__ float2 s_t16[16];
  __shared__ float2 s_t8[8];
  int img = blockIdx.x, tid = threadIdx.x;
  if (tid < 128){ float sn,cs; sincosf((float)tid*0.04908738521234052f,&sn,&cs); s_tw[tid]=make_float2(cs,-sn); }
  if (tid < 16) { float sn,cs; sincosf((float)tid*0.39269908169872414f,&sn,&cs); s_t16[tid]=make_float2(cs,-sn); }
  if (tid < 8)  { float sn,cs; sincosf((float)tid*0.7853981633974483f ,&sn,&cs); s_t8[tid]=make_float2(cs,-sn); }
  const float* xp = xt + (size_t)img*16384;
  // pack rows: sA[hp*128+w] = x[2hp][w] + i x[2hp+1][w]
  #pragma unroll
  for (int it=0; it<8; ++it){
    int j = it*1024+tid; int hp=j>>7, w=j&127;
    sA[j] = make_float2(xp[hp*256 + w], xp[hp*256 + 128 + w]);
  }
  __syncthreads();
  // row stage 1
  #pragma unroll
  for (int it=0; it<8; ++it){
    int i = it*1024+tid; int hp=i>>7, j=i&127, n2=j>>4, k1=j&15;
    float2 acc = make_float2(0.f,0.f);
    const float2* row = sA + hp*128 + n2;
    #pragma unroll
    for (int n1=0;n1<16;++n1) acc = cfma_(row[8*n1], s_t16[(n1*k1)&15], acc);
    sB[i] = cmul_(acc, s_tw[(n2*k1)&127]);
  }
  __syncthreads();
  // row stage 2
  #pragma unroll
  for (int it=0; it<8; ++it){
    int i = it*1024+tid; int hp=i>>7, k=i&127, k1=k&15, k2=k>>4;
    float2 acc = make_float2(0.f,0.f);
    const float2* u = sB + hp*128 + k1;
    #pragma unroll
    for (int n2=0;n2<8;++n2) acc = cfma_(u[16*n2], s_t8[(n2*k2)&7], acc);
    sA[i] = acc;
  }
  __syncthreads();
  // col stage 1 with on-the-fly unpack (reads sA, writes sB: no inner barrier)
  #pragma unroll
  for (int it=0; it<9; ++it){
    int i = it*1024+tid;
    if (i < 8320){
      int wf=i>>7, j=i&127, n2=j>>4, k1=j&15;
      int j2 = (128-wf)&127;
      int par = n2&1;
      float2 acc = make_float2(0.f,0.f);
      #pragma unroll
      for (int n1=0;n1<16;++n1){
        int hp = 4*n1 + (n2>>1);
        float2 Z1 = sA[hp*128+wf];
        float2 Z2 = sA[hp*128+j2];
        float yr = par ? (Z1.y+Z2.y) : (Z1.x+Z2.x);
        float yi = par ? (Z2.x-Z1.x) : (Z1.y-Z2.y);
        acc = cfma_(make_float2(yr,yi), s_t16[(n1*k1)&15], acc);
      }
      sB[i] = cmul_(acc, s_tw[(n2*k1)&127]);
    }
  }
  __syncthreads();
  // col stage 2 + scaled store
  float2* Xp = X + (size_t)img*8320;
  #pragma unroll
  for (int it=0; it<9; ++it){
    int i = it*1024+tid;
    if (i < 8320){
      int wf=i>>7, k=i&127, k1=k&15, k2=k>>4;
      float2 acc = make_float2(0.f,0.f);
      const float2* u = sB + wf*128 + k1;
      #pragma unroll
      for (int n2=0;n2<8;++n2) acc = cfma_(u[16*n2], s_t8[(n2*k2)&7], acc);
      Xp[i] = make_float2(acc.x*(1.f/256.f), acc.y*(1.f/256.f));
    }
  }
}

// ---------------- scan stage (split kernels) --------------------------------
// k_proj: project ch0/1 in place for one (b,t) image; accumulate pair-norm
// into norms[bt*2+ofs]. Grid (128, 33), 256 thr.
__global__ __launch_bounds__(256) void k_proj(float2* __restrict__ X,
                                              const float* __restrict__ gky,
                                              const float* __restrict__ gkx,
                                              const float* __restrict__ k2,
                                              float* __restrict__ norms, int ofs){
  int bt = blockIdx.x;
  int r = blockIdx.y*256 + threadIdx.x;
  float acc = 0.f;
  if (r < 8320){
    size_t base = (size_t)bt*66560 + r;
    float2 u = X[base], v = X[base+8320];
    float ky=gky[r], kx=gkx[r], ik2=1.f/k2[r];
    float dr=(ky*u.x+kx*v.x)*ik2, di=(ky*u.y+kx*v.y)*ik2;
    u.x-=ky*dr; u.y-=ky*di; v.x-=kx*dr; v.y-=kx*di;
    X[base]=u; X[base+8320]=v;
    acc = u.x*u.x+u.y*u.y+v.x*v.x+v.y*v.y;
  }
  #pragma unroll
  for (int off=32; off; off>>=1) acc += __shfl_down(acc, off);
  __shared__ float red[4];
  int wid=threadIdx.x>>6, lane=threadIdx.x&63;
  if (lane==0) red[wid]=acc;
  __syncthreads();
  if (threadIdx.x==0) atomicAdd(&norms[bt*2+ofs], red[0]+red[1]+red[2]+red[3]);
}

// k_normS: |.|^2 over channels 2..7 of one (b,t). Grid (128, 25), 256 thr.
__global__ __launch_bounds__(256) void k_normS(const float2* __restrict__ X,
                                               float* __restrict__ norms, int ofs){
  int bt = blockIdx.x;
  int e0 = 16640 + blockIdx.y*2048 + threadIdx.x;
  float acc = 0.f;
  #pragma unroll
  for (int i=0; i<8; ++i){
    int e = e0 + i*256;
    if (e < 66560){
      float2 x = X[(size_t)bt*66560 + e];
      acc = fmaf(x.x,x.x,fmaf(x.y,x.y,acc));
    }
  }
  #pragma unroll
  for (int off=32; off; off>>=1) acc += __shfl_down(acc, off);
  __shared__ float red[4];
  int wid=threadIdx.x>>6, lane=threadIdx.x&63;
  if (lane==0) red[wid]=acc;
  __syncthreads();
  if (threadIdx.x==0) atomicAdd(&norms[bt*2+ofs], red[0]+red[1]+red[2]+red[3]);
}

// k_scan: pure streaming recurrence h[t] = a*h[t-1] + x[t], in place.
__global__ __launch_bounds__(256) void k_scan(float2* __restrict__ X,
                                              const float2* __restrict__ A2){
  int tid = blockIdx.x*256 + threadIdx.x;
  if (tid >= 266240) return;
  int b = tid/66560, cr = tid - b*66560;
  float2 a = A2[tid];
  float2* p = X + (size_t)b*2129920 + cr;
  float hr=0.f, hi=0.f;
  #pragma unroll
  for (int t=0; t<32; ++t){
    float2 x = p[(size_t)t*66560];
    float nr = fmaf(a.x,hr,fmaf(-a.y,hi,x.x));
    float nn = fmaf(a.x,hi,fmaf( a.y,hr,x.y));
    hr=nr; hi=nn;
    p[(size_t)t*66560] = make_float2(hr,hi);
  }
}

// ---------------- inverse irfft2, CT 16x8, pack trick, ping-pong LDS --------
__global__ __launch_bounds__(1024) void k_fft_inv(const float2* __restrict__ X,
                                                  const float* __restrict__ norms,
                                                  float* __restrict__ out){
  __shared__ float2 sA[8320];
  __shared__ float2 sB[8320];
  __shared__ float2 s_tw[128];
  __shared__ float2 s_t16[16];
  __shared__ float2 s_t8[8];
  int img = blockIdx.x, tid = threadIdx.x;
  if (tid < 128){ float sn,cs; sincosf((float)tid*0.04908738521234052f,&sn,&cs); s_tw[tid]=make_float2(cs,sn); }
  if (tid < 16) { float sn,cs; sincosf((float)tid*0.39269908169872414f,&sn,&cs); s_t16[tid]=make_float2(cs,sn); }
  if (tid < 8)  { float sn,cs; sincosf((float)tid*0.7853981633974483f ,&sn,&cs); s_t8[tid]=make_float2(cs,sn); }
  const float2* Xp = X + (size_t)img*8320;
  #pragma unroll
  for (int it=0; it<9; ++it){ int i=it*1024+tid; if(i<8320) sA[i]=Xp[i]; }
  int bt = img >> 3;
  float scale = sqrtf(norms[bt*2]) / (sqrtf(norms[bt*2+1]) + 1e-6f) * (1.f/128.f);
  __syncthreads();
  // inv col stage 1 (reads sA, writes sB)
  #pragma unroll
  for (int it=0; it<9; ++it){
    int i = it*1024+tid;
    if (i < 8320){
      int wf=i>>7, j=i&127, n2=j>>4, k1=j&15;
      float2 acc = make_float2(0.f,0.f);
      const float2* row = sA + wf*128 + n2;
      #pragma unroll
      for (int n1=0;n1<16;++n1) acc = cfma_(row[8*n1], s_t16[(n1*k1)&15], acc);
      sB[i] = cmul_(acc, s_tw[(n2*k1)&127]);
    }
  }
  __syncthreads();
  // inv col stage 2 -> y[wf][h] (scaled) (reads sB, writes sA)
  #pragma unroll
  for (int it=0; it<9; ++it){
    int i = it*1024+tid;
    if (i < 8320){
      int wf=i>>7, h=i&127, k1=h&15, k2=h>>4;
      float2 acc = make_float2(0.f,0.f);
      const float2* u = sB + wf*128 + k1;
      #pragma unroll
      for (int n2=0;n2<8;++n2) acc = cfma_(u[16*n2], s_t8[(n2*k2)&7], acc);
      sA[i] = make_float2(acc.x*scale, acc.y*scale);
    }
  }
  __syncthreads();
  // inv row stage 1 with on-the-fly Hermitian pack (reads sA, writes sB)
  #pragma unroll
  for (int it=0; it<8; ++it){
    int i = it*1024+tid; int hp=i>>7, j=i&127, n2=j>>4, k1=j&15;
    float2 acc = make_float2(0.f,0.f);
    #pragma unroll
    for (int n1=0;n1<16;++n1){
      int wfp = 8*n1 + n2;
      int neg = wfp > 64;
      int jj = neg ? 128-wfp : wfp;
      float2 Av = sA[jj*128 + 2*hp];
      float2 Bv = sA[jj*128 + 2*hp + 1];
      if (jj == 0 || jj == 64){ Av.y = 0.f; Bv.y = 0.f; }
      float zr = neg ? (Av.x + Bv.y) : (Av.x - Bv.y);
      float zi = neg ? (Bv.x - Av.y) : (Av.y + Bv.x);
      acc = cfma_(make_float2(zr,zi), s_t16[(n1*k1)&15], acc);
    }
    sB[hp*128 + j] = cmul_(acc, s_tw[(n2*k1)&127]);
  }
  __syncthreads();
  // inv row stage 2 -> store
  float* op = out + (size_t)img*16384;
  #pragma unroll
  for (int it=0; it<8; ++it){
    int i = it*1024+tid; int hp=i>>7, w=i&127, k1=w&15, k2=w>>4;
    float2 acc = make_float2(0.f,0.f);
    const float2* u = sB + hp*128 + k1;
    #pragma unroll
    for (int n2=0;n2<8;++n2) acc = cfma_(u[16*n2], s_t8[(n2*k2)&7], acc);
    op[hp*256 + w]       = acc.x;
    op[hp*256 + 128 + w] = acc.y;
  }
}

// ---------------------------------------------------------------------------
extern "C" void kernel_launch(void* const* d_in, const int* in_sizes, int n_in,
                              void* d_out, int out_size, void* d_ws, size_t ws_size,
                              hipStream_t stream) {
  const float* x_seq = (const float*)d_in[0];
  const float* dt    = (const float*)d_in[1];
  const float* pw1   = (const float*)d_in[2];
  const float* pb1   = (const float*)d_in[3];
  const float* pw2   = (const float*)d_in[4];
  const float* pb2   = (const float*)d_in[5];
  const float* c1w   = (const float*)d_in[6];
  const float* c1b   = (const float*)d_in[7];
  const float* c2w   = (const float*)d_in[8];
  const float* c2b   = (const float*)d_in[9];
  const float* c3w   = (const float*)d_in[10];
  float* out = (float*)d_out;
  float* ws  = (float*)d_ws;

  const size_t XFH_F  = 17039360;                 // 65*128*1024 float2 in floats
  const size_t TAIL_F = 532480 + 3*8320 + 16 + 256;
  size_t avail_f = ws_size / 4;

  int chunk = 16;
  for (int c = 128; c >= 16; c >>= 1){
    size_t scratch = (size_t)3*c*262144;
    size_t R = scratch > XFH_F ? scratch : XFH_F;
    if (R + TAIL_F <= avail_f){ chunk = c; break; }
  }
  size_t Rsz = (size_t)3*chunk*262144; if (Rsz < XFH_F) Rsz = XFH_F;

  float*  Aa   = ws + Rsz;
  float*  GKY  = Aa + 532480;
  float*  GKX  = GKY + 8320;
  float*  K2   = GKX + 8320;
  float*  S3   = K2  + 8320;
  float*  NORMS= S3  + 16;

  float2* XFH = (float2*)ws;
  float2* A2  = (float2*)Aa;

  float* CZ1  = ws;
  float* CGZ2 = ws + (size_t)chunk*262144;
  float* CGZ1 = ws + (size_t)2*chunk*262144;

  k_setup_misc<<<1, 256, 0, stream>>>(c3w, S3, NORMS);
  k_setup_grid<<<33, 256, 0, stream>>>(dt, pw1, pb1, pw2, pb2, GKY, GKX, K2, A2);

  dim3 cb(32,8), cg(4,8,chunk);
  for (int n0 = 0; n0 < 128; n0 += chunk){
    const float* xin = x_seq + (size_t)n0*8*16384;
    float*       xtp = out   + (size_t)n0*8*16384;   // XT staged in d_out
    k_conv<8,16,0><<<cg, cb, 0, stream>>>(xin, c1w, c1b, nullptr, nullptr, CZ1, n0);
    k_conv<16,16,1><<<cg, cb, 0, stream>>>(CZ1, c2w, c2b, S3, nullptr, CGZ2, n0);
    k_conv<16,16,2><<<cg, cb, 0, stream>>>(CGZ2, c2w, nullptr, CZ1, nullptr, CGZ1, n0);
    k_conv<16,8,3><<<cg, cb, 0, stream>>>(CGZ1, c1w, nullptr, xin, dt, xtp, n0);
  }

  k_fft_fwd<<<1024, 1024, 0, stream>>>(out, XFH);

  k_proj <<<dim3(128,33), 256, 0, stream>>>((float2*)XFH, GKY, GKX, K2, NORMS, 0);
  k_normS<<<dim3(128,25), 256, 0, stream>>>((const float2*)XFH, NORMS, 0);
  k_scan <<<1040, 256, 0, stream>>>((float2*)XFH, A2);
  k_proj <<<dim3(128,33), 256, 0, stream>>>((float2*)XFH, GKY, GKX, K2, NORMS, 1);
  k_normS<<<dim3(128,25), 256, 0, stream>>>((const float2*)XFH, NORMS, 1);

  k_fft_inv<<<1024, 1024, 0, stream>>>(XFH, NORMS, out);
}